// Round 6
// baseline (132.556 us; speedup 1.0000x reference)
//
#include <hip/hip_runtime.h>
#include <hip/hip_fp16.h>

#define NB 4
#define NT 16
#define NN 2048
#define NM 64
#define NK 32
#define NC 1024

// ROCm 7.2 hip_fp16.h has no __hmax2 — emit v_pk_max_f16 directly.
static __device__ inline __half2 h2max(__half2 a, __half2 b) {
    unsigned int ai = *(unsigned int*)&a, bi = *(unsigned int*)&b, di;
    asm("v_pk_max_f16 %0, %1, %2" : "=v"(di) : "v"(ai), "v"(bi));
    return *(__half2*)&di;
}

// DPP-based wave64 max reduce step (verified in R5): after the chain,
// lane 63 holds the wave max.
#define DPP_MAX_STEP(v, ctrl)                                                   \
    do {                                                                        \
        const int _mv = __builtin_amdgcn_update_dpp(                            \
            __float_as_int(v), __float_as_int(v), (ctrl), 0xf, 0xf, false);     \
        (v) = fmaxf((v), __int_as_float(_mv));                                  \
    } while (0)

static __device__ inline float readlane_f(float x, int l) {
    return __int_as_float(__builtin_amdgcn_readlane(__float_as_int(x), l));
}

// ---------------------------------------------------------------------------
// Kernel A: FPS, one 256-thr block (4 waves) per frame, 8 contiguous pts per
// thread in registers. vs R5: NO sP point array in LDS at all — the per-wave
// candidate written to LDS carries (key, x, y, z); the next anchor's coords
// come from a 4-candidate key+coords tournament in registers, removing the
// dependent sP[last*3] read from the serial per-round chain. Tie-break
// semantics identical to the verified R4/R5 versions (value DPP max ->
// lowest-lane ballot within wave; u64 (d2bits<<32 | 2047-idx) max across
// waves). Arithmetic (_rn, no FMA) identical to the verified versions.
// ---------------------------------------------------------------------------
__global__ __launch_bounds__(256) void fps_kernel(const float* __restrict__ xyzs,
                                                  float* __restrict__ out_xyz) {
    const int bt = blockIdx.x;
    const float* pts = xyzs + (size_t)bt * NN * 3;
    __shared__ unsigned long long sKey[2][4];
    __shared__ __align__(16) float sCand[2][4][4];
    __shared__ float sAnchor[NM * 3];
    __shared__ float sInit[3];
    const int tid = threadIdx.x;
    const int lane = tid & 63, wave = tid >> 6;
    float wpt[24];
    {
        const float4* pv = (const float4*)pts + (size_t)tid * 6;
        #pragma unroll
        for (int i = 0; i < 6; ++i) {
            const float4 f = pv[i];
            wpt[4 * i + 0] = f.x; wpt[4 * i + 1] = f.y; wpt[4 * i + 2] = f.z; wpt[4 * i + 3] = f.w;
        }
    }
    float px[8], py[8], pz[8], d2v[8];
    #pragma unroll
    for (int j = 0; j < 8; ++j) {
        px[j] = wpt[3 * j + 0]; py[j] = wpt[3 * j + 1]; pz[j] = wpt[3 * j + 2];
        d2v[j] = 1e10f;
    }
    if (tid == 0) { sInit[0] = px[0]; sInit[1] = py[0]; sInit[2] = pz[0]; }
    __syncthreads();
    float ax = sInit[0], ay = sInit[1], az = sInit[2];   // anchor coords live in regs
    for (int it = 0; it < NM; ++it) {
        if (tid == 0) {
            sAnchor[it * 3 + 0] = ax; sAnchor[it * 3 + 1] = ay; sAnchor[it * 3 + 2] = az;
        }
        float bv = -1.0f; int bj = 0;
        #pragma unroll
        for (int j = 0; j < 8; ++j) {
            const float dx = __fsub_rn(px[j], ax), dy = __fsub_rn(py[j], ay), dz = __fsub_rn(pz[j], az);
            const float d = __fadd_rn(__fadd_rn(__fmul_rn(dx, dx), __fmul_rn(dy, dy)), __fmul_rn(dz, dz));
            d2v[j] = fminf(d2v[j], d);
            if (d2v[j] > bv) { bv = d2v[j]; bj = j; }  // strict > -> first j wins
        }
        // wave value-max via DPP, then exact first-index tie-break via ballot:
        float v = bv;
        DPP_MAX_STEP(v, 0x111);   // row_shr:1
        DPP_MAX_STEP(v, 0x112);   // row_shr:2
        DPP_MAX_STEP(v, 0x114);   // row_shr:4
        DPP_MAX_STEP(v, 0x118);   // row_shr:8
        DPP_MAX_STEP(v, 0x142);   // row_bcast:15
        DPP_MAX_STEP(v, 0x143);   // row_bcast:31
        const float vmax = readlane_f(v, 63);
        const unsigned long long tied = __ballot(bv == vmax);
        const int src = (int)(__ffsll((long long)tied) - 1);   // lowest lane = lowest idx
        // per-lane candidate coords: explicit cndmask tree over bj (0..7)
        const float cx0 = (bj & 1) ? px[1] : px[0], cx1 = (bj & 1) ? px[3] : px[2];
        const float cx2 = (bj & 1) ? px[5] : px[4], cx3 = (bj & 1) ? px[7] : px[6];
        const float cy0 = (bj & 1) ? py[1] : py[0], cy1 = (bj & 1) ? py[3] : py[2];
        const float cy2 = (bj & 1) ? py[5] : py[4], cy3 = (bj & 1) ? py[7] : py[6];
        const float cz0 = (bj & 1) ? pz[1] : pz[0], cz1 = (bj & 1) ? pz[3] : pz[2];
        const float cz2 = (bj & 1) ? pz[5] : pz[4], cz3 = (bj & 1) ? pz[7] : pz[6];
        const float cxa = (bj & 2) ? cx1 : cx0, cxb = (bj & 2) ? cx3 : cx2;
        const float cya = (bj & 2) ? cy1 : cy0, cyb = (bj & 2) ? cy3 : cy2;
        const float cza = (bj & 2) ? cz1 : cz0, czb = (bj & 2) ? cz3 : cz2;
        const float cx = (bj & 4) ? cxb : cxa;
        const float cy = (bj & 4) ? cyb : cya;
        const float cz = (bj & 4) ? czb : cza;
        const int idx = tid * 8 + bj;
        const int widx = __builtin_amdgcn_readlane(idx, src);
        const float wx = readlane_f(cx, src);
        const float wy = readlane_f(cy, src);
        const float wz = readlane_f(cz, src);
        const int par = it & 1;
        if (lane == 0) {
            sKey[par][wave] = ((unsigned long long)__float_as_uint(vmax) << 32)
                            | (unsigned)(NN - 1 - widx);
            *(float4*)&sCand[par][wave][0] = make_float4(wx, wy, wz, 0.0f);
        }
        __syncthreads();
        // 4-candidate tournament on (key, coords) — no dependent point lookup
        unsigned long long bk = sKey[par][0];
        float4 bc = *(const float4*)&sCand[par][0][0];
        #pragma unroll
        for (int i = 1; i < 4; ++i) {
            const unsigned long long ki = sKey[par][i];
            const float4 ci = *(const float4*)&sCand[par][i][0];
            if (ki > bk) { bk = ki; bc = ci; }
        }
        ax = bc.x; ay = bc.y; az = bc.z;
    }
    __syncthreads();
    for (int i = tid; i < NM * 3; i += 256)
        out_xyz[bt * NM * 3 + i] = sAnchor[i];
}

// ---------------------------------------------------------------------------
// Kernel B: ball query only (unchanged from verified R4/R5). One wave per
// (bt,m,tap) query -> 48 packed half2 displacement words into d_ws.
// ---------------------------------------------------------------------------
__global__ __launch_bounds__(256) void bq_kernel(const float* __restrict__ xyzs,
                                                 const float* __restrict__ anchors,
                                                 unsigned int* __restrict__ disp) {
    const int tid = threadIdx.x;
    const int lane = tid & 63, w = tid >> 6;
    const int q = blockIdx.x * 4 + w;      // (bt*NM + m)*3 + tap
    const int bt = q / (NM * 3);
    const int r = q - bt * (NM * 3);
    const int m = r / 3, tap = r - m * 3;
    const int b = bt >> 4, t = bt & 15;
    __shared__ float sD[4][3][NK];
    const float ax = anchors[(bt * NM + m) * 3 + 0];
    const float ay = anchors[(bt * NM + m) * 3 + 1];
    const float az = anchors[(bt * NM + m) * 3 + 2];
    int tsrc = t + tap - 1;
    tsrc = tsrc < 0 ? 0 : (tsrc > NT - 1 ? NT - 1 : tsrc);
    const float* npts = xyzs + ((size_t)(b * NT + tsrc)) * NN * 3;
    int cnt = 0;
    for (int rr = 0; rr < NN / 64 && cnt < NK; ++rr) {
        const int n = rr * 64 + lane;
        const float dx = __fsub_rn(npts[n * 3 + 0], ax);
        const float dy = __fsub_rn(npts[n * 3 + 1], ay);
        const float dz = __fsub_rn(npts[n * 3 + 2], az);
        const float d2v = __fadd_rn(__fadd_rn(__fmul_rn(dx, dx), __fmul_rn(dy, dy)), __fmul_rn(dz, dz));
        const bool valid = d2v < 0.49f;    // f32(0.7*0.7)
        const unsigned long long mask = __ballot(valid);
        const int pos = cnt + (int)__popcll(mask & ((1ull << lane) - 1ull));
        if (valid && pos < NK) {
            sD[w][0][pos] = dx; sD[w][1][pos] = dy; sD[w][2][pos] = dz;
        }
        cnt += (int)__popcll(mask);
    }
    if (cnt < NK) {   // pad with first valid disp (or neigh[0]-anchor if none)
        float fx, fy, fz;
        if (cnt > 0) {
            fx = sD[w][0][0]; fy = sD[w][1][0]; fz = sD[w][2][0];
        } else {
            fx = __fsub_rn(npts[0], ax); fy = __fsub_rn(npts[1], ay); fz = __fsub_rn(npts[2], az);
        }
        if (lane >= cnt && lane < NK) {
            sD[w][0][lane] = fx; sD[w][1][lane] = fy; sD[w][2][lane] = fz;
        }
    }
    // repack f32 -> half2 pairs along k; layout [x:16][y:16][z:16] u32 words
    if (lane < 48) {
        const int c = lane >> 4, j = lane & 15;
        const __half2 hv = __float22half2_rn(make_float2(sD[w][c][2 * j], sD[w][c][2 * j + 1]));
        disp[(size_t)q * 48 + lane] = *(const unsigned int*)&hv;
    }
}

// ---------------------------------------------------------------------------
// Kernel C: conv + k-maxpool + tap-sum. vs R5: wave = 2 m x 4 ch (8192 waves,
// 2048 blocks = 8 blocks/CU -> 8 waves/SIMD), tile loaded in two 6xb128
// chunks to keep transient regs low, __launch_bounds__(256,8) to cap VGPR
// at the 8-waves/SIMD budget. No LDS, no barriers.
// ---------------------------------------------------------------------------
__global__ __launch_bounds__(256, 8) void conv_kernel(const unsigned int* __restrict__ disp,
                                                      const float* __restrict__ wd,
                                                      float* __restrict__ feat) {
    const int blk = blockIdx.x;            // 2048 = 64bt * 8mh * 4cq
    const int bt = blk >> 5;
    const int inner = blk & 31;
    const int mh = inner >> 2, cq = inner & 3;
    const int tid = threadIdx.x;
    const int lane = tid & 63, w = tid >> 6;
    const int m0 = mh * 8 + w * 2;
    const int c0 = cq * 256 + lane;        // channels c0 + {0,64,128,192}
    __half2 wx[4], wy[4], wz[4]; float ww[4];
    #pragma unroll
    for (int r = 0; r < 4; ++r) {
        const float4 wv = ((const float4*)wd)[c0 + 64 * r];
        wx[r] = __float2half2_rn(wv.x);
        wy[r] = __float2half2_rn(wv.y);
        wz[r] = __float2half2_rn(wv.z);
        ww[r] = wv.w;
    }
    float acc[4][2];
    #pragma unroll
    for (int r = 0; r < 4; ++r) { acc[r][0] = 0.0f; acc[r][1] = 0.0f; }

    #pragma unroll
    for (int mi = 0; mi < 2; ++mi) {
        #pragma unroll
        for (int tap = 0; tap < 3; ++tap) {
            const uint4* dp = (const uint4*)(disp + ((size_t)((bt * NM + m0 + mi) * 3 + tap)) * 48);
            __half2 a[4];
            #pragma unroll
            for (int h = 0; h < 2; ++h) {     // two half-tiles: j 0..7, 8..15
                const uint4 ux0 = dp[2 * h],     ux1 = dp[2 * h + 1];
                const uint4 uy0 = dp[4 + 2 * h], uy1 = dp[5 + 2 * h];
                const uint4 uz0 = dp[8 + 2 * h], uz1 = dp[9 + 2 * h];
                const unsigned int X[8] = {ux0.x, ux0.y, ux0.z, ux0.w, ux1.x, ux1.y, ux1.z, ux1.w};
                const unsigned int Y[8] = {uy0.x, uy0.y, uy0.z, uy0.w, uy1.x, uy1.y, uy1.z, uy1.w};
                const unsigned int Z[8] = {uz0.x, uz0.y, uz0.z, uz0.w, uz1.x, uz1.y, uz1.z, uz1.w};
                #pragma unroll
                for (int j = 0; j < 8; ++j) {
                    const __half2 hx = *(const __half2*)&X[j];
                    const __half2 hy = *(const __half2*)&Y[j];
                    const __half2 hz = *(const __half2*)&Z[j];
                    #pragma unroll
                    for (int r = 0; r < 4; ++r) {
                        const __half2 s = __hfma2(wx[r], hx, __hfma2(wy[r], hy, __hmul2(wz[r], hz)));
                        a[r] = (h == 0 && j == 0) ? s : h2max(a[r], s);
                    }
                }
            }
            const float dtf = (float)(tap - 1);
            #pragma unroll
            for (int r = 0; r < 4; ++r) {
                const float mx = fmaxf(__low2float(a[r]), __high2float(a[r]));
                acc[r][mi] += fmaxf(0.0f, mx + ww[r] * dtf);   // relu/max/+const commute
            }
        }
    }
    #pragma unroll
    for (int r = 0; r < 4; ++r) {
        float* dst = feat + ((size_t)bt * NC + c0 + 64 * r) * NM + m0;
        *(float2*)dst = make_float2(acc[r][0], acc[r][1]);
    }
}

extern "C" void kernel_launch(void* const* d_in, const int* in_sizes, int n_in,
                              void* d_out, int out_size, void* d_ws, size_t ws_size,
                              hipStream_t stream) {
    const float* xyzs = (const float*)d_in[0];
    const float* wd   = (const float*)d_in[1];
    float* out_xyz = (float*)d_out;
    float* featp   = out_xyz + NB * NT * NM * 3;         // new_features region
    unsigned int* dispw = (unsigned int*)d_ws;           // 12288*48*4 B = 2.36 MB
    hipLaunchKernelGGL(fps_kernel, dim3(NB * NT), dim3(256), 0, stream, xyzs, out_xyz);
    hipLaunchKernelGGL(bq_kernel, dim3(NB * NT * NM * 3 / 4), dim3(256), 0, stream,
                       xyzs, out_xyz, dispw);
    hipLaunchKernelGGL(conv_kernel, dim3(2048), dim3(256), 0, stream,
                       dispw, wd, featp);
}

// Round 7
// 129.415 us; speedup vs baseline: 1.0243x; 1.0243x over previous
//
#include <hip/hip_runtime.h>
#include <hip/hip_fp16.h>

#define NB 4
#define NT 16
#define NN 2048
#define NM 64
#define NK 32
#define NC 1024

// ROCm 7.2 hip_fp16.h has no __hmax2 — emit v_pk_max_f16 directly.
static __device__ inline __half2 h2max(__half2 a, __half2 b) {
    unsigned int ai = *(unsigned int*)&a, bi = *(unsigned int*)&b, di;
    asm("v_pk_max_f16 %0, %1, %2" : "=v"(di) : "v"(ai), "v"(bi));
    return *(__half2*)&di;
}

// DPP-based wave64 max reduce step (verified R5/R6): after the chain,
// lane 63 holds the wave max.
#define DPP_MAX_STEP(v, ctrl)                                                   \
    do {                                                                        \
        const int _mv = __builtin_amdgcn_update_dpp(                            \
            __float_as_int(v), __float_as_int(v), (ctrl), 0xf, 0xf, false);     \
        (v) = fmaxf((v), __int_as_float(_mv));                                  \
    } while (0)

static __device__ inline float readlane_f(float x, int l) {
    return __int_as_float(__builtin_amdgcn_readlane(__float_as_int(x), l));
}

// ---------------------------------------------------------------------------
// Kernel A: FPS (R6 tournament version, correctness-verified in R6).
// One 256-thr block (4 waves) per frame, 8 contiguous pts/thread in regs.
// Candidate (key, x, y, z) carried through the LDS sidecar; next anchor from
// a 4-candidate register tournament — no dependent point lookup in the
// serial chain. Tie-break + arithmetic (_rn, no FMA) bit-exact vs reference.
// ---------------------------------------------------------------------------
__global__ __launch_bounds__(256) void fps_kernel(const float* __restrict__ xyzs,
                                                  float* __restrict__ out_xyz) {
    const int bt = blockIdx.x;
    const float* pts = xyzs + (size_t)bt * NN * 3;
    __shared__ unsigned long long sKey[2][4];
    __shared__ __align__(16) float sCand[2][4][4];
    __shared__ float sAnchor[NM * 3];
    __shared__ float sInit[3];
    const int tid = threadIdx.x;
    const int lane = tid & 63, wave = tid >> 6;
    float wpt[24];
    {
        const float4* pv = (const float4*)pts + (size_t)tid * 6;
        #pragma unroll
        for (int i = 0; i < 6; ++i) {
            const float4 f = pv[i];
            wpt[4 * i + 0] = f.x; wpt[4 * i + 1] = f.y; wpt[4 * i + 2] = f.z; wpt[4 * i + 3] = f.w;
        }
    }
    float px[8], py[8], pz[8], d2v[8];
    #pragma unroll
    for (int j = 0; j < 8; ++j) {
        px[j] = wpt[3 * j + 0]; py[j] = wpt[3 * j + 1]; pz[j] = wpt[3 * j + 2];
        d2v[j] = 1e10f;
    }
    if (tid == 0) { sInit[0] = px[0]; sInit[1] = py[0]; sInit[2] = pz[0]; }
    __syncthreads();
    float ax = sInit[0], ay = sInit[1], az = sInit[2];   // anchor coords live in regs
    for (int it = 0; it < NM; ++it) {
        if (tid == 0) {
            sAnchor[it * 3 + 0] = ax; sAnchor[it * 3 + 1] = ay; sAnchor[it * 3 + 2] = az;
        }
        float bv = -1.0f; int bj = 0;
        #pragma unroll
        for (int j = 0; j < 8; ++j) {
            const float dx = __fsub_rn(px[j], ax), dy = __fsub_rn(py[j], ay), dz = __fsub_rn(pz[j], az);
            const float d = __fadd_rn(__fadd_rn(__fmul_rn(dx, dx), __fmul_rn(dy, dy)), __fmul_rn(dz, dz));
            d2v[j] = fminf(d2v[j], d);
            if (d2v[j] > bv) { bv = d2v[j]; bj = j; }  // strict > -> first j wins
        }
        // wave value-max via DPP, then exact first-index tie-break via ballot:
        float v = bv;
        DPP_MAX_STEP(v, 0x111);   // row_shr:1
        DPP_MAX_STEP(v, 0x112);   // row_shr:2
        DPP_MAX_STEP(v, 0x114);   // row_shr:4
        DPP_MAX_STEP(v, 0x118);   // row_shr:8
        DPP_MAX_STEP(v, 0x142);   // row_bcast:15
        DPP_MAX_STEP(v, 0x143);   // row_bcast:31
        const float vmax = readlane_f(v, 63);
        const unsigned long long tied = __ballot(bv == vmax);
        const int src = (int)(__ffsll((long long)tied) - 1);   // lowest lane = lowest idx
        // per-lane candidate coords: explicit cndmask tree over bj (0..7)
        const float cx0 = (bj & 1) ? px[1] : px[0], cx1 = (bj & 1) ? px[3] : px[2];
        const float cx2 = (bj & 1) ? px[5] : px[4], cx3 = (bj & 1) ? px[7] : px[6];
        const float cy0 = (bj & 1) ? py[1] : py[0], cy1 = (bj & 1) ? py[3] : py[2];
        const float cy2 = (bj & 1) ? py[5] : py[4], cy3 = (bj & 1) ? py[7] : py[6];
        const float cz0 = (bj & 1) ? pz[1] : pz[0], cz1 = (bj & 1) ? pz[3] : pz[2];
        const float cz2 = (bj & 1) ? pz[5] : pz[4], cz3 = (bj & 1) ? pz[7] : pz[6];
        const float cxa = (bj & 2) ? cx1 : cx0, cxb = (bj & 2) ? cx3 : cx2;
        const float cya = (bj & 2) ? cy1 : cy0, cyb = (bj & 2) ? cy3 : cy2;
        const float cza = (bj & 2) ? cz1 : cz0, czb = (bj & 2) ? cz3 : cz2;
        const float cx = (bj & 4) ? cxb : cxa;
        const float cy = (bj & 4) ? cyb : cya;
        const float cz = (bj & 4) ? czb : cza;
        const int idx = tid * 8 + bj;
        const int widx = __builtin_amdgcn_readlane(idx, src);
        const float wx = readlane_f(cx, src);
        const float wy = readlane_f(cy, src);
        const float wz = readlane_f(cz, src);
        const int par = it & 1;
        if (lane == 0) {
            sKey[par][wave] = ((unsigned long long)__float_as_uint(vmax) << 32)
                            | (unsigned)(NN - 1 - widx);
            *(float4*)&sCand[par][wave][0] = make_float4(wx, wy, wz, 0.0f);
        }
        __syncthreads();
        // 4-candidate tournament on (key, coords) — no dependent point lookup
        unsigned long long bk = sKey[par][0];
        float4 bc = *(const float4*)&sCand[par][0][0];
        #pragma unroll
        for (int i = 1; i < 4; ++i) {
            const unsigned long long ki = sKey[par][i];
            const float4 ci = *(const float4*)&sCand[par][i][0];
            if (ki > bk) { bk = ki; bc = ci; }
        }
        ax = bc.x; ay = bc.y; az = bc.z;
    }
    __syncthreads();
    for (int i = tid; i < NM * 3; i += 256)
        out_xyz[bt * NM * 3 + i] = sAnchor[i];
}

// ---------------------------------------------------------------------------
// Kernel B: ball query only (unchanged, verified R4-R6). One wave per
// (bt,m,tap) query -> 48 packed half2 displacement words into d_ws.
// ---------------------------------------------------------------------------
__global__ __launch_bounds__(256) void bq_kernel(const float* __restrict__ xyzs,
                                                 const float* __restrict__ anchors,
                                                 unsigned int* __restrict__ disp) {
    const int tid = threadIdx.x;
    const int lane = tid & 63, w = tid >> 6;
    const int q = blockIdx.x * 4 + w;      // (bt*NM + m)*3 + tap
    const int bt = q / (NM * 3);
    const int r = q - bt * (NM * 3);
    const int m = r / 3, tap = r - m * 3;
    const int b = bt >> 4, t = bt & 15;
    __shared__ float sD[4][3][NK];
    const float ax = anchors[(bt * NM + m) * 3 + 0];
    const float ay = anchors[(bt * NM + m) * 3 + 1];
    const float az = anchors[(bt * NM + m) * 3 + 2];
    int tsrc = t + tap - 1;
    tsrc = tsrc < 0 ? 0 : (tsrc > NT - 1 ? NT - 1 : tsrc);
    const float* npts = xyzs + ((size_t)(b * NT + tsrc)) * NN * 3;
    int cnt = 0;
    for (int rr = 0; rr < NN / 64 && cnt < NK; ++rr) {
        const int n = rr * 64 + lane;
        const float dx = __fsub_rn(npts[n * 3 + 0], ax);
        const float dy = __fsub_rn(npts[n * 3 + 1], ay);
        const float dz = __fsub_rn(npts[n * 3 + 2], az);
        const float d2v = __fadd_rn(__fadd_rn(__fmul_rn(dx, dx), __fmul_rn(dy, dy)), __fmul_rn(dz, dz));
        const bool valid = d2v < 0.49f;    // f32(0.7*0.7)
        const unsigned long long mask = __ballot(valid);
        const int pos = cnt + (int)__popcll(mask & ((1ull << lane) - 1ull));
        if (valid && pos < NK) {
            sD[w][0][pos] = dx; sD[w][1][pos] = dy; sD[w][2][pos] = dz;
        }
        cnt += (int)__popcll(mask);
    }
    if (cnt < NK) {   // pad with first valid disp (or neigh[0]-anchor if none)
        float fx, fy, fz;
        if (cnt > 0) {
            fx = sD[w][0][0]; fy = sD[w][1][0]; fz = sD[w][2][0];
        } else {
            fx = __fsub_rn(npts[0], ax); fy = __fsub_rn(npts[1], ay); fz = __fsub_rn(npts[2], az);
        }
        if (lane >= cnt && lane < NK) {
            sD[w][0][lane] = fx; sD[w][1][lane] = fy; sD[w][2][lane] = fz;
        }
    }
    // repack f32 -> half2 pairs along k; layout [x:16][y:16][z:16] u32 words
    if (lane < 48) {
        const int c = lane >> 4, j = lane & 15;
        const __half2 hv = __float22half2_rn(make_float2(sD[w][c][2 * j], sD[w][c][2 * j + 1]));
        disp[(size_t)q * 48 + lane] = *(const unsigned int*)&hv;
    }
}

// ---------------------------------------------------------------------------
// Kernel C: conv + k-maxpool + tap-sum. R5 shape (1024 blocks, wave = 4 m x
// 4 ch) + explicit 2-tile software pipeline: issue all 12 dwordx4 loads of
// tile t+1 into the spare buffer, then run the 256 pk-f16 ops of tile t
// (~512 cyc issue >> load latency -> fully hidden). ~140 VGPR; launch_bounds
// (256,3) budgets 170. No LDS, no barriers.
// ---------------------------------------------------------------------------
__global__ __launch_bounds__(256, 3) void conv_kernel(const unsigned int* __restrict__ disp,
                                                      const float* __restrict__ wd,
                                                      float* __restrict__ feat) {
    const int blk = blockIdx.x;            // 1024 = 64bt * 4mh * 4cq
    const int bt = blk >> 4;
    const int inner = blk & 15;
    const int mh = inner >> 2, cq = inner & 3;
    const int tid = threadIdx.x;
    const int lane = tid & 63, w = tid >> 6;
    const int m0 = mh * 16 + w * 4;
    const int c0 = cq * 256 + lane;        // channels c0 + {0,64,128,192}
    __half2 wx[4], wy[4], wz[4]; float ww[4];
    #pragma unroll
    for (int r = 0; r < 4; ++r) {
        const float4 wv = ((const float4*)wd)[c0 + 64 * r];
        wx[r] = __float2half2_rn(wv.x);
        wy[r] = __float2half2_rn(wv.y);
        wz[r] = __float2half2_rn(wv.z);
        ww[r] = wv.w;
    }
    float acc[4][4];
    #pragma unroll
    for (int r = 0; r < 4; ++r)
        #pragma unroll
        for (int mi = 0; mi < 4; ++mi) acc[r][mi] = 0.0f;

    // tiles t = mi*3 + tap, contiguous at base (layout: q = (bt*NM+m)*3+tap)
    const uint4* base = (const uint4*)(disp + (size_t)((bt * NM + m0) * 3) * 48);
    uint4 bufA[12], bufB[12];
    #pragma unroll
    for (int i = 0; i < 12; ++i) bufA[i] = base[i];     // tile 0
    #pragma unroll
    for (int t = 0; t < 12; ++t) {
        const uint4* cur = (t & 1) ? bufB : bufA;
        uint4*       nxt = (t & 1) ? bufA : bufB;
        if (t < 11) {                                    // prefetch tile t+1
            const uint4* np = base + (size_t)(t + 1) * 12;
            #pragma unroll
            for (int i = 0; i < 12; ++i) nxt[i] = np[i];
        }
        const unsigned int* uw = (const unsigned int*)cur;  // X[0..15] Y[16..31] Z[32..47]
        __half2 a[4];
        #pragma unroll
        for (int j = 0; j < 16; ++j) {
            const __half2 hx = *(const __half2*)&uw[j];
            const __half2 hy = *(const __half2*)&uw[16 + j];
            const __half2 hz = *(const __half2*)&uw[32 + j];
            #pragma unroll
            for (int r = 0; r < 4; ++r) {
                const __half2 s = __hfma2(wx[r], hx, __hfma2(wy[r], hy, __hmul2(wz[r], hz)));
                a[r] = (j == 0) ? s : h2max(a[r], s);
            }
        }
        const int mi = t / 3, tap = t - mi * 3;
        const float dtf = (float)(tap - 1);
        #pragma unroll
        for (int r = 0; r < 4; ++r) {
            const float mx = fmaxf(__low2float(a[r]), __high2float(a[r]));
            acc[r][mi] += fmaxf(0.0f, mx + ww[r] * dtf);   // relu/max/+const commute
        }
    }
    #pragma unroll
    for (int r = 0; r < 4; ++r) {
        float* dst = feat + ((size_t)bt * NC + c0 + 64 * r) * NM + m0;
        *(float4*)dst = make_float4(acc[r][0], acc[r][1], acc[r][2], acc[r][3]);
    }
}

extern "C" void kernel_launch(void* const* d_in, const int* in_sizes, int n_in,
                              void* d_out, int out_size, void* d_ws, size_t ws_size,
                              hipStream_t stream) {
    const float* xyzs = (const float*)d_in[0];
    const float* wd   = (const float*)d_in[1];
    float* out_xyz = (float*)d_out;
    float* featp   = out_xyz + NB * NT * NM * 3;         // new_features region
    unsigned int* dispw = (unsigned int*)d_ws;           // 12288*48*4 B = 2.36 MB
    hipLaunchKernelGGL(fps_kernel, dim3(NB * NT), dim3(256), 0, stream, xyzs, out_xyz);
    hipLaunchKernelGGL(bq_kernel, dim3(NB * NT * NM * 3 / 4), dim3(256), 0, stream,
                       xyzs, out_xyz, dispw);
    hipLaunchKernelGGL(conv_kernel, dim3(1024), dim3(256), 0, stream,
                       dispw, wd, featp);
}